// Round 1
// baseline (42996.747 us; speedup 1.0000x reference)
//
#include <hip/hip_runtime.h>
#include <hip/hip_cooperative_groups.h>
#include <hip/hip_bf16.h>

namespace cg = cooperative_groups;

// Problem dims
#define B_   1024
#define T_   256
#define D_   128
#define H_   512
#define G_   2048   // 4*H
#define K_   640    // D + H  (fused [x | h] contraction dim)

// Decomposition: 256 blocks = NB_ batch tiles x NH_ gate slices
#define NB_  4
#define NH_  64
#define BT_  256    // batch rows per block
#define JS_  8      // h-units per block (=> 32 gate rows)
#define CK_  32     // k-chunk staged in LDS per inner iteration
#define PITCH_ 33   // LDS pitch: 33 % 32 == 1 -> conflict-free column reads

__device__ __forceinline__ float sigmoidf_(float v) {
    return 1.0f / (1.0f + __expf(-v));
}

// Fuse W_ih|W_hh into Wf[2048][640], bias into biasf[2048]
__global__ void prep_kernel(const float* __restrict__ Wih, const float* __restrict__ Whh,
                            const float* __restrict__ bih, const float* __restrict__ bhh,
                            float* __restrict__ Wf, float* __restrict__ biasf) {
    int idx = blockIdx.x * 256 + threadIdx.x;
    const int total = G_ * K_;
    if (idx < total) {
        int row = idx / K_;
        int k   = idx - row * K_;
        Wf[idx] = (k < D_) ? Wih[row * D_ + k] : Whh[row * H_ + (k - D_)];
    }
    if (idx < G_) biasf[idx] = bih[idx] + bhh[idx];
}

// Persistent cooperative LSTM kernel.
// Block (bi,hi): batch rows [bi*256, bi*256+256), h-units [hi*8, hi*8+8).
// Thread (jj = tid>>6, cc = tid&63): h-unit j0+jj, batch cols {b0+cc+64*g, g=0..3}.
__global__ void __launch_bounds__(512, 2) lstm_kernel(
    const float* __restrict__ x,      // [B][T][D]
    const float* __restrict__ Wf,     // [2048][640]
    const float* __restrict__ biasf,  // [2048]
    float* __restrict__ hbuf)         // [2][B][H] double buffer
{
    __shared__ float in_lds[BT_][PITCH_];

    const int blk = blockIdx.x;
    const int bi  = blk >> 6;          // 0..3
    const int hi  = blk & 63;          // 0..63
    const int b0  = bi * BT_;
    const int j0  = hi * JS_;
    const int tid = threadIdx.x;
    const int jj  = tid >> 6;          // 0..7 (== wave id -> W rows wave-uniform)
    const int cc  = tid & 63;          // 0..63
    const int j   = j0 + jj;

    const float* wr[4];
    float bias[4];
#pragma unroll
    for (int q = 0; q < 4; ++q) {
        wr[q]   = Wf + (size_t)(q * H_ + j) * K_;
        bias[q] = biasf[q * H_ + j];
    }

    float cst[4] = {0.f, 0.f, 0.f, 0.f};

    const int f4  = tid & 7;   // float4 slot within 32-k chunk
    const int bb0 = tid >> 3;  // 0..63

    cg::grid_group grid = cg::this_grid();

    for (int t = 0; t < T_; ++t) {
        float acc[4][4];
#pragma unroll
        for (int q = 0; q < 4; ++q)
#pragma unroll
            for (int g = 0; g < 4; ++g) acc[q][g] = bias[q];

        const float* hprev = hbuf + (size_t)((t & 1) ^ 1) * (B_ * H_);
        const int nch = (t == 0) ? (D_ / CK_) : (K_ / CK_);  // t=0: h==0, skip h chunks

        for (int ch = 0; ch < nch; ++ch) {
            const int k0 = ch * CK_;

            // ---- stage [x_t | h_prev] chunk into LDS (coalesced 16B loads) ----
#pragma unroll
            for (int gg = 0; gg < 4; ++gg) {
                const int bb = bb0 + 64 * gg;
                const int b  = b0 + bb;
                float4 v;
                if (k0 < D_) {
                    v = *reinterpret_cast<const float4*>(
                        x + ((size_t)b * T_ + t) * D_ + (k0 + f4 * 4));
                } else {
                    v = *reinterpret_cast<const float4*>(
                        hprev + (size_t)b * H_ + (k0 - D_) + f4 * 4);
                }
                const int kb = f4 * 4;
                in_lds[bb][kb + 0] = v.x;
                in_lds[bb][kb + 1] = v.y;
                in_lds[bb][kb + 2] = v.z;
                in_lds[bb][kb + 3] = v.w;
            }
            __syncthreads();

            // ---- accumulate: 4 gate rows x 4 batch cols per thread ----
            const float* bg[4];
#pragma unroll
            for (int g = 0; g < 4; ++g) bg[g] = &in_lds[cc + 64 * g][0];

#pragma unroll
            for (int kk4 = 0; kk4 < CK_ / 4; ++kk4) {
                float4 w4[4];
#pragma unroll
                for (int q = 0; q < 4; ++q)
                    w4[q] = *reinterpret_cast<const float4*>(wr[q] + k0 + kk4 * 4);
#pragma unroll
                for (int u = 0; u < 4; ++u) {
                    float in4[4];
#pragma unroll
                    for (int g = 0; g < 4; ++g) in4[g] = bg[g][kk4 * 4 + u];
#pragma unroll
                    for (int q = 0; q < 4; ++q) {
                        const float wv = reinterpret_cast<const float*>(&w4[q])[u];
#pragma unroll
                        for (int g = 0; g < 4; ++g)
                            acc[q][g] = fmaf(wv, in4[g], acc[q][g]);
                    }
                }
            }
            __syncthreads();
        }

        // ---- pointwise LSTM cell + h write ----
        float* hcur = hbuf + (size_t)(t & 1) * (B_ * H_);
#pragma unroll
        for (int g = 0; g < 4; ++g) {
            const float gi = sigmoidf_(acc[0][g]);
            const float gf = sigmoidf_(acc[1][g]);
            const float gc = tanhf(acc[2][g]);
            const float go = sigmoidf_(acc[3][g]);
            const float cn = gf * cst[g] + gi * gc;
            cst[g] = cn;
            const float hn = go * tanhf(cn);
            hcur[(size_t)(b0 + cc + 64 * g) * H_ + j] = hn;
        }

        __threadfence();   // device-scope release of h before cross-XCD readers
        grid.sync();
    }
}

// features = hT @ W_feat^T + b_feat ; out = features @ W_out^T + b_out
__global__ void __launch_bounds__(256) final_kernel(
    const float* __restrict__ hT, const float* __restrict__ Wfeat,
    const float* __restrict__ bfeat, const float* __restrict__ Wout,
    const float* __restrict__ bout, float* __restrict__ out)
{
    __shared__ float hl[H_];
    __shared__ float featl[256];
    const int b   = blockIdx.x;
    const int tid = threadIdx.x;

    hl[tid]       = hT[(size_t)b * H_ + tid];
    hl[tid + 256] = hT[(size_t)b * H_ + 256 + tid];
    __syncthreads();

    float acc = bfeat[tid];
    const float* wrow = Wfeat + (size_t)tid * H_;
#pragma unroll 4
    for (int h = 0; h < H_; h += 4) {
        const float4 wv = *reinterpret_cast<const float4*>(wrow + h);
        acc += wv.x * hl[h] + wv.y * hl[h + 1] + wv.z * hl[h + 2] + wv.w * hl[h + 3];
    }
    featl[tid] = acc;
    __syncthreads();

    if (tid < 2) {
        float a = bout[tid];
        for (int f = 0; f < 256; ++f) a += featl[f] * Wout[tid * 256 + f];
        out[(size_t)b * 2 + tid] = a;
    }
}

extern "C" void kernel_launch(void* const* d_in, const int* in_sizes, int n_in,
                              void* d_out, int out_size, void* d_ws, size_t ws_size,
                              hipStream_t stream) {
    const float* x     = (const float*)d_in[0];
    const float* Wih   = (const float*)d_in[1];
    const float* Whh   = (const float*)d_in[2];
    const float* bih   = (const float*)d_in[3];
    const float* bhh   = (const float*)d_in[4];
    const float* Wfeat = (const float*)d_in[5];
    const float* bfeat = (const float*)d_in[6];
    const float* Wout  = (const float*)d_in[7];
    const float* bout  = (const float*)d_in[8];
    float* out = (float*)d_out;

    char* ws = (char*)d_ws;
    float* Wf    = (float*)ws;                                   // 2048*640*4 = 5,242,880 B
    float* biasf = (float*)(ws + 5242880);                       // 8,192 B
    float* hbuf  = (float*)(ws + 5242880 + 8192);                // 2*1024*512*4 = 4,194,304 B
    // total ws use: ~9.45 MB

    prep_kernel<<<dim3((G_ * K_ + 255) / 256), dim3(256), 0, stream>>>(
        Wih, Whh, bih, bhh, Wf, biasf);

    void* args[] = {(void*)&x, (void*)&Wf, (void*)&biasf, (void*)&hbuf};
    hipLaunchCooperativeKernel((void*)lstm_kernel, dim3(NB_ * NH_), dim3(512),
                               args, 0, stream);

    const float* hT = hbuf + (size_t)((T_ - 1) & 1) * (B_ * H_);
    final_kernel<<<dim3(B_), dim3(256), 0, stream>>>(hT, Wfeat, bfeat, Wout, bout, out);
}

// Round 2
// 23232.524 us; speedup vs baseline: 1.8507x; 1.8507x over previous
//
#include <hip/hip_runtime.h>
#include <hip/hip_cooperative_groups.h>

namespace cg = cooperative_groups;

typedef _Float16 h16;
typedef __attribute__((ext_vector_type(8))) _Float16 half8;
typedef __attribute__((ext_vector_type(4))) float f32x4;

#define B_   1024
#define T_   256
#define D_   128
#define H_   512
#define Kc_  640    // D + H (fused [x|h] contraction)
#define NR_  2048   // 4H rows, R-mapped

__device__ __forceinline__ float sigm_(float v) {
    return 1.0f / (1.0f + __expf(-v));
}
__device__ __forceinline__ float tanh_(float v) {
    v = fminf(15.0f, fmaxf(-15.0f, v));
    const float e = __expf(2.0f * v);
    return (e - 1.0f) / (e + 1.0f);
}

// Row shuffle: unit j (0..511), gate q (0..3; torch order i,f,g,o = src row q*512+j)
// R = (j>>2)*16 + (j&3)*4 + q  -> a 16-row MFMA tile = 4 units x 4 gates, and with
// C/D row = (lane>>4)*4 + reg this makes reg == gate, unit == lane>>4 (lane-local cell).
__global__ void prep_kernel(const float* __restrict__ Wih, const float* __restrict__ Whh,
                            const float* __restrict__ bih, const float* __restrict__ bhh,
                            h16* __restrict__ Wr, float* __restrict__ biasr) {
    int idx = blockIdx.x * 256 + threadIdx.x;
    if (idx < NR_ * Kc_) {
        int R = idx / Kc_, k = idx - R * Kc_;
        int Q = R >> 4, rw = R & 15;
        int j = Q * 4 + (rw >> 2), q = rw & 3;
        int src = q * H_ + j;
        float w = (k < D_) ? Wih[src * D_ + k] : Whh[src * H_ + (k - D_)];
        Wr[idx] = (h16)w;
    }
    if (idx < NR_) {
        int Q = idx >> 4, rw = idx & 15;
        int j = Q * 4 + (rw >> 2), q = rw & 3;
        int src = q * H_ + j;
        biasr[idx] = bih[src] + bhh[src];
    }
}

// Persistent cooperative LSTM. Block (ht, bt): h-units [ht*16, ht*16+16),
// batch [bt*128, bt*128+128). bt = blk&7 -> all readers of a batch-slice share an XCD.
// Wave w: hs = w>>2 (2 unit-subs of 8), bs = w&3 (4 batch-subs of 32).
// W slice (32 R-rows x 640 k fp16) lives in 160 VGPRs per wave for the whole kernel.
__global__ void __launch_bounds__(512, 2) lstm_kernel(
    const float* __restrict__ x,      // [B][T][D] fp32
    const h16*  __restrict__ Wr,      // [2048][640] fp16 (R-mapped)
    const float* __restrict__ biasr,  // [2048]
    h16* __restrict__ hbuf)           // [2][B][H] fp16 double buffer
{
    __shared__ __align__(16) char lds[3][16384];   // triple-buffered [128 b][64 k] fp16

    const int blk = blockIdx.x;
    const int bt  = blk & 7;
    const int ht  = blk >> 3;
    const int tid = threadIdx.x;
    const int w   = tid >> 6, l = tid & 63;
    const int hs  = w >> 2, bs = w & 3;
    const int ll  = l & 15, lh = l >> 4;
    const int ju  = ht * 16 + hs * 8;     // wave's h-unit base
    const int bb  = bt * 128 + bs * 32;   // wave's global batch base

    // ---- W slice -> registers (once) ----
    half8 warr[2][20];
#pragma unroll
    for (int rt = 0; rt < 2; ++rt) {
        const h16* wbase = Wr + (size_t)(ju * 4 + rt * 16 + ll) * Kc_ + lh * 8;
#pragma unroll
        for (int kc = 0; kc < 20; ++kc)
            warr[rt][kc] = *reinterpret_cast<const half8*>(wbase + kc * 32);
    }
    f32x4 bias4[2];
#pragma unroll
    for (int rt = 0; rt < 2; ++rt)
        bias4[rt] = *reinterpret_cast<const f32x4*>(biasr + ju * 4 + rt * 16 + lh * 4);

    float cst[2][2] = {{0.f, 0.f}, {0.f, 0.f}};
    f32x4 acc[2][2];

    // staging ids: thread handles 32B of one (row, 16k-seg)
    const int srow = tid >> 2;               // local batch row 0..127
    const int sseg = tid & 3;                // 16-elem k segment
    const int sgb  = bt * 128 + srow;        // global batch
    const int swz  = (srow & 7) << 4;
    const int sby0 = srow * 128 + sseg * 32;

    half8 sreg0, sreg1;

    auto stage_load = [&](int t, int ch, const h16* hprev) {
        if (ch < 2) {  // x part, k = ch*64 + sseg*16
            const float* xp = x + ((size_t)sgb * T_ + t) * D_ + ch * 64 + sseg * 16;
            f32x4 a = *reinterpret_cast<const f32x4*>(xp);
            f32x4 b = *reinterpret_cast<const f32x4*>(xp + 4);
            f32x4 c = *reinterpret_cast<const f32x4*>(xp + 8);
            f32x4 d = *reinterpret_cast<const f32x4*>(xp + 12);
            half8 r0, r1;
#pragma unroll
            for (int u = 0; u < 4; ++u) {
                r0[u] = (h16)a[u]; r0[4 + u] = (h16)b[u];
                r1[u] = (h16)c[u]; r1[4 + u] = (h16)d[u];
            }
            sreg0 = r0; sreg1 = r1;
        } else {       // h part, hk = ch*64 - 128 + sseg*16
            const h16* hp = hprev + (size_t)sgb * H_ + (ch * 64 - 128) + sseg * 16;
            sreg0 = *reinterpret_cast<const half8*>(hp);
            sreg1 = *reinterpret_cast<const half8*>(hp + 8);
        }
    };
    auto stage_write = [&](int bufi) {
        *reinterpret_cast<half8*>(lds[bufi] + (sby0 ^ swz))        = sreg0;
        *reinterpret_cast<half8*>(lds[bufi] + ((sby0 + 16) ^ swz)) = sreg1;
    };
    auto compute = [&](int bufi, int kcbase) {  // kcbase must be compile-time const
#pragma unroll
        for (int kk = 0; kk < 2; ++kk) {
            half8 bf[2];
#pragma unroll
            for (int ct = 0; ct < 2; ++ct) {
                const int brow = bs * 32 + ct * 16 + ll;
                int byte = brow * 128 + kk * 64 + lh * 16;
                byte ^= (brow & 7) << 4;
                bf[ct] = *reinterpret_cast<const half8*>(lds[bufi] + byte);
            }
#pragma unroll
            for (int rt = 0; rt < 2; ++rt)
#pragma unroll
                for (int ct = 0; ct < 2; ++ct)
                    acc[rt][ct] = __builtin_amdgcn_mfma_f32_16x16x32_f16(
                        warr[rt][kcbase + kk], bf[ct], acc[rt][ct], 0, 0, 0);
        }
    };

    cg::grid_group grid = cg::this_grid();

    for (int t = 0; t < T_; ++t) {
        const h16* hprev = hbuf + (size_t)((t & 1) ^ 1) * (B_ * H_);
        h16*       hcur  = hbuf + (size_t)(t & 1) * (B_ * H_);

#pragma unroll
        for (int rt = 0; rt < 2; ++rt)
#pragma unroll
            for (int ct = 0; ct < 2; ++ct) acc[rt][ct] = bias4[rt];

        if (t == 0) {   // h==0: only the 2 x-chunks
            stage_load(0, 0, hprev); stage_write(0);
#pragma unroll
            for (int ch = 0; ch < 2; ++ch) {
                if (ch + 1 < 2) stage_load(0, ch + 1, hprev);
                __syncthreads();
                if (ch + 1 < 2) stage_write((ch + 1) % 3);
                compute(ch % 3, ch * 2);
            }
        } else {
            stage_load(t, 0, hprev); stage_write(0);
#pragma unroll
            for (int ch = 0; ch < 10; ++ch) {
                if (ch + 1 < 10) stage_load(t, ch + 1, hprev);
                __syncthreads();
                if (ch + 1 < 10) stage_write((ch + 1) % 3);
                compute(ch % 3, ch * 2);
            }
        }

        // ---- lane-local LSTM cell: reg==gate, unit==ju+rt*4+lh, batch==bb+ct*16+ll ----
#pragma unroll
        for (int rt = 0; rt < 2; ++rt)
#pragma unroll
            for (int ct = 0; ct < 2; ++ct) {
                f32x4 g4 = acc[rt][ct];
                const float gi = sigm_(g4[0]);
                const float gf = sigm_(g4[1]);
                const float gg = tanh_(g4[2]);
                const float go = sigm_(g4[3]);
                const float c  = gf * cst[rt][ct] + gi * gg;
                cst[rt][ct] = c;
                const float h = go * tanh_(c);
                hcur[(size_t)(bb + ct * 16 + ll) * H_ + (ju + rt * 4 + lh)] = (h16)h;
            }

        __threadfence();
        grid.sync();
    }
}

// features = hT @ Wfeat^T + bfeat ; out = features @ Wout^T + bout
__global__ void __launch_bounds__(256) final_kernel(
    const h16* __restrict__ hT, const float* __restrict__ Wfeat,
    const float* __restrict__ bfeat, const float* __restrict__ Wout,
    const float* __restrict__ bout, float* __restrict__ out)
{
    __shared__ __align__(16) h16 hsh[16][512];
    __shared__ float fsh[16][256];
    const int tid = threadIdx.x;
    const int b0  = blockIdx.x * 16;

    {
        const int row = tid >> 4, seg = tid & 15;
        const half8* s8 = reinterpret_cast<const half8*>(hT + (size_t)(b0 + row) * H_ + seg * 32);
        half8* d8 = reinterpret_cast<half8*>(&hsh[row][seg * 32]);
        d8[0] = s8[0]; d8[1] = s8[1]; d8[2] = s8[2]; d8[3] = s8[3];
    }
    __syncthreads();

    float acc[16];
#pragma unroll
    for (int b = 0; b < 16; ++b) acc[b] = 0.f;
    const float* wrow = Wfeat + (size_t)tid * H_;
    for (int k8 = 0; k8 < H_ / 8; ++k8) {
        f32x4 w0 = *reinterpret_cast<const f32x4*>(wrow + k8 * 8);
        f32x4 w1 = *reinterpret_cast<const f32x4*>(wrow + k8 * 8 + 4);
#pragma unroll
        for (int b = 0; b < 16; ++b) {
            half8 h8 = *reinterpret_cast<const half8*>(&hsh[b][k8 * 8]);
#pragma unroll
            for (int u = 0; u < 4; ++u) {
                acc[b] = fmaf(w0[u], (float)h8[u], acc[b]);
                acc[b] = fmaf(w1[u], (float)h8[4 + u], acc[b]);
            }
        }
    }
    const float bf = bfeat[tid];
#pragma unroll
    for (int b = 0; b < 16; ++b) fsh[b][tid] = acc[b] + bf;
    __syncthreads();

    if (tid < 32) {
        const int b = tid >> 1, oc = tid & 1;
        float a = bout[oc];
        const float* wo = Wout + oc * 256;
        for (int f = 0; f < 256; ++f) a = fmaf(wo[f], fsh[b][f], a);
        out[(size_t)(b0 + b) * 2 + oc] = a;
    }
}

extern "C" void kernel_launch(void* const* d_in, const int* in_sizes, int n_in,
                              void* d_out, int out_size, void* d_ws, size_t ws_size,
                              hipStream_t stream) {
    const float* x     = (const float*)d_in[0];
    const float* Wih   = (const float*)d_in[1];
    const float* Whh   = (const float*)d_in[2];
    const float* bih   = (const float*)d_in[3];
    const float* bhh   = (const float*)d_in[4];
    const float* Wfeat = (const float*)d_in[5];
    const float* bfeat = (const float*)d_in[6];
    const float* Wout  = (const float*)d_in[7];
    const float* bout  = (const float*)d_in[8];
    float* out = (float*)d_out;

    char* ws = (char*)d_ws;
    h16*   Wr    = (h16*)ws;                        // 2048*640*2 = 2,621,440 B
    float* biasr = (float*)(ws + 2621440);          // 8,192 B
    h16*   hbuf  = (h16*)(ws + 2621440 + 8192);     // 2*1024*512*2 = 2,097,152 B

    prep_kernel<<<dim3((NR_ * Kc_ + 255) / 256), dim3(256), 0, stream>>>(
        Wih, Whh, bih, bhh, Wr, biasr);

    void* args[] = {(void*)&x, (void*)&Wr, (void*)&biasr, (void*)&hbuf};
    hipLaunchCooperativeKernel((void*)lstm_kernel, dim3(256), dim3(512), args, 0, stream);

    const h16* hT = hbuf + (size_t)((T_ - 1) & 1) * (B_ * H_);
    final_kernel<<<dim3(B_ / 16), dim3(256), 0, stream>>>(hT, Wfeat, bfeat, Wout, bout, out);
}

// Round 3
// 5062.722 us; speedup vs baseline: 8.4928x; 4.5889x over previous
//
#include <hip/hip_runtime.h>

typedef _Float16 h16;
typedef __attribute__((ext_vector_type(8))) _Float16 half8;
typedef __attribute__((ext_vector_type(4))) float f32x4;
typedef unsigned long long ull;

#define B_   1024
#define T_   256
#define D_   128
#define H_   512
#define Kc_  640    // D + H (fused [x|h] contraction)
#define NR_  2048   // 4H rows, R-mapped
#define CHK_ 128    // k elems per LDS chunk
#define AGENT_ __HIP_MEMORY_SCOPE_AGENT

__device__ __forceinline__ float sigm_(float v) {
    return 1.0f / (1.0f + __expf(-v));
}
__device__ __forceinline__ float tanh_(float v) {
    v = fminf(15.0f, fmaxf(-15.0f, v));
    const float e = __expf(2.0f * v);
    return (e - 1.0f) / (e + 1.0f);
}

// Row shuffle: unit j, gate q (torch order i,f,g,o = src row q*512+j):
// R = (j>>2)*16 + (j&3)*4 + q. With C/D row=(lane>>4)*4+reg this makes
// reg == gate, unit == lane-local -> pointwise cell needs no cross-lane.
__global__ void prep_kernel(const float* __restrict__ Wih, const float* __restrict__ Whh,
                            const float* __restrict__ bih, const float* __restrict__ bhh,
                            h16* __restrict__ Wr, float* __restrict__ biasr,
                            unsigned* __restrict__ bar) {
    int idx = blockIdx.x * 256 + threadIdx.x;
    if (idx < NR_ * Kc_) {
        int R = idx / Kc_, k = idx - R * Kc_;
        int Q = R >> 4, rw = R & 15;
        int j = Q * 4 + (rw >> 2), q = rw & 3;
        int src = q * H_ + j;
        float w = (k < D_) ? Wih[src * D_ + k] : Whh[src * H_ + (k - D_)];
        Wr[idx] = (h16)w;
    }
    if (idx < NR_) {
        int Q = idx >> 4, rw = idx & 15;
        int j = Q * 4 + (rw >> 2), q = rw & 3;
        int src = q * H_ + j;
        biasr[idx] = bih[src] + bhh[src];
    }
    if (idx < 128)  // zero the group-barrier counters (agent scope so lstm sees it)
        __hip_atomic_store(bar + idx, 0u, __ATOMIC_RELAXED, AGENT_);
}

// Persistent LSTM, cooperative launch (co-residency) but NO grid.sync.
// Block (ht, bt): h-units [ht*16,+16), batch [bt*128,+128).
// Group = 32 blocks sharing bt; h all-gathered per step through L3 via
// agent-scope relaxed atomics; per-group monotonic-counter barrier.
__global__ void __launch_bounds__(512, 2) lstm_kernel(
    const float* __restrict__ x,      // [B][T][D] fp32
    const h16*  __restrict__ Wr,      // [2048][640] fp16 (R-mapped)
    const float* __restrict__ biasr,  // [2048]
    h16* __restrict__ hbuf,           // [2][B][H] fp16 double buffer
    unsigned* __restrict__ bar)       // [8] group counters (stride 16 uints)
{
    __shared__ __align__(16) char lds[3][32768];   // 3 bufs x [128 rows][128 k] fp16

    const int blk = blockIdx.x;
    const int bt  = blk & 7;
    const int ht  = blk >> 3;
    const int tid = threadIdx.x;
    const int w   = tid >> 6, l = tid & 63;
    const int hs  = w >> 2, bs = w & 3;
    const int ll  = l & 15, lh = l >> 4;
    const int ju  = ht * 16 + hs * 8;     // wave's h-unit base
    const int bb  = bt * 128 + bs * 32;   // wave's global batch base

    // ---- W slice -> registers (once, reused all 256 steps) ----
    half8 warr[2][20];
#pragma unroll
    for (int rt = 0; rt < 2; ++rt) {
        const h16* wbase = Wr + (size_t)(ju * 4 + rt * 16 + ll) * Kc_ + lh * 8;
#pragma unroll
        for (int kc = 0; kc < 20; ++kc)
            warr[rt][kc] = *reinterpret_cast<const half8*>(wbase + kc * 32);
    }
    f32x4 bias4[2];
#pragma unroll
    for (int rt = 0; rt < 2; ++rt)
        bias4[rt] = *reinterpret_cast<const f32x4*>(biasr + ju * 4 + rt * 16 + lh * 4);

    float cst[2][2] = {{0.f, 0.f}, {0.f, 0.f}};
    f32x4 acc[2][2];

    // staging ids: thread owns 64B of one LDS row (row srow, 32-k seg sseg)
    const int srow = tid >> 2;               // 0..127
    const int sseg = tid & 3;                // 0..3
    const int sgb  = bt * 128 + srow;        // global batch row staged
    const int swz  = (srow & 7) << 4;

    half8 sA[4], sB[4];

    auto load_x = [&](int t, half8* s) {
        const float* xp = x + ((size_t)sgb * T_ + t) * D_ + sseg * 32;
#pragma unroll
        for (int i = 0; i < 4; ++i) {
            f32x4 a = *reinterpret_cast<const f32x4*>(xp + i * 8);
            f32x4 b = *reinterpret_cast<const f32x4*>(xp + i * 8 + 4);
            half8 r;
#pragma unroll
            for (int u = 0; u < 4; ++u) { r[u] = (h16)a[u]; r[4 + u] = (h16)b[u]; }
            s[i] = r;
        }
    };
    auto load_h = [&](const h16* hprev, int ch, half8* s) {
        ull* hp = (ull*)(hprev + (size_t)sgb * H_ + (ch - 1) * CHK_ + sseg * 32);
#pragma unroll
        for (int i = 0; i < 4; ++i) {
            ull v0 = __hip_atomic_load(hp + i * 2,     __ATOMIC_RELAXED, AGENT_);
            ull v1 = __hip_atomic_load(hp + i * 2 + 1, __ATOMIC_RELAXED, AGENT_);
            half8 r;
            reinterpret_cast<ull*>(&r)[0] = v0;
            reinterpret_cast<ull*>(&r)[1] = v1;
            s[i] = r;
        }
    };
    auto stage_write = [&](int bufi, half8* s) {
        char* base = lds[bufi];
#pragma unroll
        for (int i = 0; i < 4; ++i)
            *reinterpret_cast<half8*>(base + ((srow * 256 + sseg * 64 + i * 16) ^ swz)) = s[i];
    };
    auto compute = [&](int bufi, int kcbase) {   // call with literals only
#pragma unroll
        for (int kk = 0; kk < 4; ++kk) {
            half8 bfv[2];
#pragma unroll
            for (int ct = 0; ct < 2; ++ct) {
                const int brow = bs * 32 + ct * 16 + ll;
                int byte = brow * 256 + kk * 64 + lh * 16;
                byte ^= (brow & 7) << 4;
                bfv[ct] = *reinterpret_cast<const half8*>(lds[bufi] + byte);
            }
#pragma unroll
            for (int rt = 0; rt < 2; ++rt)
#pragma unroll
                for (int ct = 0; ct < 2; ++ct)
                    acc[rt][ct] = __builtin_amdgcn_mfma_f32_16x16x32_f16(
                        warr[rt][kcbase + kk], bfv[ct], acc[rt][ct], 0, 0, 0);
        }
    };

    unsigned* barp = bar + bt * 16;

    for (int t = 0; t < T_; ++t) {
        const h16* hprev = hbuf + (size_t)((t & 1) ^ 1) * (B_ * H_);
        h16*       hcur  = hbuf + (size_t)(t & 1) * (B_ * H_);

#pragma unroll
        for (int rt = 0; rt < 2; ++rt)
#pragma unroll
            for (int ct = 0; ct < 2; ++ct) acc[rt][ct] = bias4[rt];

        if (t == 0) {   // h==0: only the x chunk
            load_x(0, sA); stage_write(0, sA);
            __syncthreads();
            compute(0, 0);
        } else {
            // 5 chunks of 128 k; loads issued one barrier-interval ahead
            load_x(t, sA); stage_write(0, sA);
            load_h(hprev, 1, sB);
            __syncthreads();
            stage_write(1, sB); load_h(hprev, 2, sA); compute(0, 0);
            __syncthreads();
            stage_write(2, sA); load_h(hprev, 3, sB); compute(1, 4);
            __syncthreads();
            stage_write(0, sB); load_h(hprev, 4, sA); compute(2, 8);
            __syncthreads();
            stage_write(1, sA);                        compute(0, 12);
            __syncthreads();
            compute(1, 16);
        }

        // ---- lane-local cell (reg==gate), h -> LDS bounce (buf2 is free) ----
        h16* hsl = reinterpret_cast<h16*>(lds[2]);   // [128 local batch][16 units]
#pragma unroll
        for (int rt = 0; rt < 2; ++rt)
#pragma unroll
            for (int ct = 0; ct < 2; ++ct) {
                f32x4 g4 = acc[rt][ct];
                const float gi = sigm_(g4[0]);
                const float gf = sigm_(g4[1]);
                const float gg = tanh_(g4[2]);
                const float go = sigm_(g4[3]);
                const float c  = gf * cst[rt][ct] + gi * gg;
                cst[rt][ct] = c;
                const float h = go * tanh_(c);
                hsl[(bs * 32 + ct * 16 + ll) * 16 + hs * 8 + rt * 4 + lh] = (h16)h;
            }
        __syncthreads();

        // packed 8B agent-scope (write-through) h store: 4 units per thread
        {
            const int bl = tid >> 2, seg = tid & 3;
            ull pk = *reinterpret_cast<const ull*>(hsl + bl * 16 + seg * 4);
            ull* dst = reinterpret_cast<ull*>(hcur + (size_t)(bt * 128 + bl) * H_ + ht * 16 + seg * 4);
            __hip_atomic_store(dst, pk, __ATOMIC_RELAXED, AGENT_);
        }

        if (t < T_ - 1) {
            // ---- per-group barrier: monotonic counter, target 32*(t+1) ----
            __syncthreads();   // drains the h stores (vmcnt 0) for every wave
            if (tid == 0) {
                __hip_atomic_fetch_add(barp, 1u, __ATOMIC_RELEASE, AGENT_);
                const unsigned tgt = 32u * (unsigned)(t + 1);
                while (__hip_atomic_load(barp, __ATOMIC_ACQUIRE, AGENT_) < tgt)
                    __builtin_amdgcn_s_sleep(1);
            }
            __syncthreads();
        }
    }
}

// features = hT @ Wfeat^T + bfeat ; out = features @ Wout^T + bout
__global__ void __launch_bounds__(256) final_kernel(
    const h16* __restrict__ hT, const float* __restrict__ Wfeat,
    const float* __restrict__ bfeat, const float* __restrict__ Wout,
    const float* __restrict__ bout, float* __restrict__ out)
{
    __shared__ __align__(16) h16 hsh[16][512];
    __shared__ float fsh[16][256];
    const int tid = threadIdx.x;
    const int b0  = blockIdx.x * 16;

    {
        const int row = tid >> 4, seg = tid & 15;
        const half8* s8 = reinterpret_cast<const half8*>(hT + (size_t)(b0 + row) * H_ + seg * 32);
        half8* d8 = reinterpret_cast<half8*>(&hsh[row][seg * 32]);
        d8[0] = s8[0]; d8[1] = s8[1]; d8[2] = s8[2]; d8[3] = s8[3];
    }
    __syncthreads();

    float acc[16];
#pragma unroll
    for (int b = 0; b < 16; ++b) acc[b] = 0.f;
    const float* wrow = Wfeat + (size_t)tid * H_;
    for (int k8 = 0; k8 < H_ / 8; ++k8) {
        f32x4 w0 = *reinterpret_cast<const f32x4*>(wrow + k8 * 8);
        f32x4 w1 = *reinterpret_cast<const f32x4*>(wrow + k8 * 8 + 4);
#pragma unroll
        for (int b = 0; b < 16; ++b) {
            half8 h8 = *reinterpret_cast<const half8*>(&hsh[b][k8 * 8]);
#pragma unroll
            for (int u = 0; u < 4; ++u) {
                acc[b] = fmaf(w0[u], (float)h8[u], acc[b]);
                acc[b] = fmaf(w1[u], (float)h8[4 + u], acc[b]);
            }
        }
    }
    const float bf = bfeat[tid];
#pragma unroll
    for (int b = 0; b < 16; ++b) fsh[b][tid] = acc[b] + bf;
    __syncthreads();

    if (tid < 32) {
        const int b = tid >> 1, oc = tid & 1;
        float a = bout[oc];
        const float* wo = Wout + oc * 256;
        for (int f = 0; f < 256; ++f) a = fmaf(wo[f], fsh[b][f], a);
        out[(size_t)(b0 + b) * 2 + oc] = a;
    }
}

extern "C" void kernel_launch(void* const* d_in, const int* in_sizes, int n_in,
                              void* d_out, int out_size, void* d_ws, size_t ws_size,
                              hipStream_t stream) {
    const float* x     = (const float*)d_in[0];
    const float* Wih   = (const float*)d_in[1];
    const float* Whh   = (const float*)d_in[2];
    const float* bih   = (const float*)d_in[3];
    const float* bhh   = (const float*)d_in[4];
    const float* Wfeat = (const float*)d_in[5];
    const float* bfeat = (const float*)d_in[6];
    const float* Wout  = (const float*)d_in[7];
    const float* bout  = (const float*)d_in[8];
    float* out = (float*)d_out;

    char* ws = (char*)d_ws;
    h16*      Wr    = (h16*)ws;                          // 2,621,440 B
    float*    biasr = (float*)(ws + 2621440);            // 8,192 B
    h16*      hbuf  = (h16*)(ws + 2621440 + 8192);       // 2,097,152 B
    unsigned* bar   = (unsigned*)(ws + 2621440 + 8192 + 2097152);  // 512 B

    prep_kernel<<<dim3((NR_ * Kc_ + 255) / 256), dim3(256), 0, stream>>>(
        Wih, Whh, bih, bhh, Wr, biasr, bar);

    void* args[] = {(void*)&x, (void*)&Wr, (void*)&biasr, (void*)&hbuf, (void*)&bar};
    hipLaunchCooperativeKernel((void*)lstm_kernel, dim3(256), dim3(512), args, 0, stream);

    const h16* hT = hbuf + (size_t)(B_ * H_);   // slot (T-1)&1 == 1
    final_kernel<<<dim3(B_ / 16), dim3(256), 0, stream>>>(hT, Wfeat, bfeat, Wout, bout, out);
}

// Round 4
// 4195.740 us; speedup vs baseline: 10.2477x; 1.2066x over previous
//
#include <hip/hip_runtime.h>

typedef _Float16 h16;
typedef __attribute__((ext_vector_type(8))) _Float16 half8;
typedef __attribute__((ext_vector_type(4))) float f32x4;
typedef unsigned long long ull;

#define B_   1024
#define T_   256
#define D_   128
#define H_   512
#define Kc_  640    // D + H
#define NR_  2048   // 4H rows, R-mapped
#define AGENT_ __HIP_MEMORY_SCOPE_AGENT

__device__ __forceinline__ float sigm_(float v) {
    return 1.0f / (1.0f + __expf(-v));
}
__device__ __forceinline__ float tanh_(float v) {
    v = fminf(15.0f, fmaxf(-15.0f, v));
    const float e = __expf(2.0f * v);
    return (e - 1.0f) / (e + 1.0f);
}

// Row shuffle: unit j, gate q (torch order i,f,g,o = src row q*512+j):
// R = (j>>2)*16 + (j&3)*4 + q. With C/D row=(lane>>4)*4+reg: reg==gate,
// unit lane-local -> pointwise cell needs no cross-lane.
__global__ void prep_kernel(const float* __restrict__ Wih, const float* __restrict__ Whh,
                            const float* __restrict__ bih, const float* __restrict__ bhh,
                            h16* __restrict__ Wr, float* __restrict__ biasr,
                            unsigned* __restrict__ bar) {
    int idx = blockIdx.x * 256 + threadIdx.x;
    if (idx < NR_ * Kc_) {
        int R = idx / Kc_, k = idx - R * Kc_;
        int Q = R >> 4, rw = R & 15;
        int j = Q * 4 + (rw >> 2), q = rw & 3;
        int src = q * H_ + j;
        float w = (k < D_) ? Wih[src * D_ + k] : Whh[src * H_ + (k - D_)];
        Wr[idx] = (h16)w;
    }
    if (idx < NR_) {
        int Q = idx >> 4, rw = idx & 15;
        int j = Q * 4 + (rw >> 2), q = rw & 3;
        int src = q * H_ + j;
        biasr[idx] = bih[src] + bhh[src];
    }
    if (idx < 512)
        __hip_atomic_store(bar + idx, 0u, __ATOMIC_RELAXED, AGENT_);
}

// Persistent LSTM, cooperative launch, custom 8-block group barriers.
// Block (bt = blk>>3, ht = blk&7): batch [bt*32,+32), units [ht*64,+64).
// Wave wv (0..7): R-rows [ht*256 + wv*32, +32) (rt 0..1), full 32-batch B tile.
// W slice (32 R-rows x 640 k fp16) resident in 160 VGPRs/lane for all 256 steps.
__global__ void __launch_bounds__(512, 2) lstm_kernel(
    const float* __restrict__ x,      // [B][T][D] fp32
    const h16*  __restrict__ Wr,      // [2048][640] fp16 (R-mapped)
    const float* __restrict__ biasr,  // [2048]
    h16* __restrict__ hbuf,           // [2][B][H] fp16 double buffer
    unsigned* __restrict__ bar)       // [32 groups x 16] counters
{
    // LDS: x tile [32 rows][16 granules], h tile [32 rows][64 granules], bounce [32][64]
    __shared__ __align__(16) char ldsx[8192];
    __shared__ __align__(16) char ldsh[32768];
    __shared__ __align__(16) char ldsb[4096];

    const int blk = blockIdx.x;
    const int bt  = blk >> 3;          // 0..31 batch tile
    const int ht  = blk & 7;           // 0..7  unit tile
    const int tid = threadIdx.x;
    const int wv  = tid >> 6, l = tid & 63;
    const int ll  = l & 15, lh = l >> 4;
    const int Rb  = ht * 256 + wv * 32;   // wave's R-row base
    const int bbase = bt * 32;            // block's global batch base

    // ---- W slice -> registers (once) ----
    half8 warr[2][20];
#pragma unroll
    for (int rt = 0; rt < 2; ++rt) {
        const h16* wbase = Wr + (size_t)(Rb + rt * 16 + ll) * Kc_ + lh * 8;
#pragma unroll
        for (int kc = 0; kc < 20; ++kc)
            warr[rt][kc] = *reinterpret_cast<const half8*>(wbase + kc * 32);
    }
    f32x4 bias4[2];
#pragma unroll
    for (int rt = 0; rt < 2; ++rt)
        bias4[rt] = *reinterpret_cast<const f32x4*>(biasr + Rb + rt * 16 + lh * 4);

    float cst[2][2] = {{0.f, 0.f}, {0.f, 0.f}};

    // staging ids: thread (srow 0..31, scol 0..15)
    const int srow = tid >> 4;
    const int scol = tid & 15;
    const int sgb  = bbase + srow;        // batch row this thread stages
    // x stage-write byte (granule = scol, Gray-permuted, row-XOR)
    const int xw_byte = (srow * 256 + ((scol ^ (scol >> 1)) * 16)) ^ ((srow & 7) << 4);

    unsigned* barp = bar + bt * 16;

    ull   hval[8];
    f32x4 xr0, xr1;

    // ---- prologue: zero h region, load+stage x(0) ----
    {
        half8 z;
#pragma unroll
        for (int u = 0; u < 8; ++u) z[u] = (h16)0.f;
        char* p = ldsh + tid * 64;
#pragma unroll
        for (int i = 0; i < 4; ++i)
            *reinterpret_cast<half8*>(p + i * 16) = z;
        const float* xp = x + (size_t)sgb * T_ * D_ + scol * 8;
        xr0 = *reinterpret_cast<const f32x4*>(xp);
        xr1 = *reinterpret_cast<const f32x4*>(xp + 4);
        half8 r;
#pragma unroll
        for (int u = 0; u < 4; ++u) { r[u] = (h16)xr0[u]; r[4 + u] = (h16)xr1[u]; }
        *reinterpret_cast<half8*>(ldsx + xw_byte) = r;
    }

    for (int t = 0; t < T_; ++t) {
        h16* hcur = hbuf + (size_t)(t & 1) * (B_ * H_);

        if (t > 0) {
            // stage h from regs loaded at end of t-1 (8B pieces, Gray+XOR swizzle)
#pragma unroll
            for (int i = 0; i < 8; ++i) {
                const int g  = i * 8 + (scol >> 1);
                const int g2 = g ^ (g >> 1);
                const int byte = (srow * 1024 + g2 * 16 + (scol & 1) * 8) ^ ((srow & 7) << 4);
                *reinterpret_cast<ull*>(ldsh + byte) = hval[i];
            }
        }
        __syncthreads();   // S1: staging complete

        f32x4 acc[2][2];
#pragma unroll
        for (int rt = 0; rt < 2; ++rt)
#pragma unroll
            for (int ct = 0; ct < 2; ++ct) acc[rt][ct] = bias4[rt];

        // ---- x part: k = 0..128 (kk 0..3) ----
#pragma unroll
        for (int kk = 0; kk < 4; ++kk) {
            half8 bf[2];
#pragma unroll
            for (int ct = 0; ct < 2; ++ct) {
                const int brow = ct * 16 + ll;
                const int ks = kk * 4 + lh;
                const int g2 = ks ^ (ks >> 1);
                const int byte = (brow * 256 + g2 * 16) ^ ((brow & 7) << 4);
                bf[ct] = *reinterpret_cast<const half8*>(ldsx + byte);
            }
#pragma unroll
            for (int rt = 0; rt < 2; ++rt)
#pragma unroll
                for (int ct = 0; ct < 2; ++ct)
                    acc[rt][ct] = __builtin_amdgcn_mfma_f32_16x16x32_f16(
                        warr[rt][kk], bf[ct], acc[rt][ct], 0, 0, 0);
        }

        // prefetch x(t+1) while h-part computes
        if (t + 1 < T_) {
            const float* xp = x + ((size_t)sgb * T_ + (t + 1)) * D_ + scol * 8;
            xr0 = *reinterpret_cast<const f32x4*>(xp);
            xr1 = *reinterpret_cast<const f32x4*>(xp + 4);
        }

        // ---- h part: k = 128..640 (kk 0..15) ----
#pragma unroll
        for (int kk = 0; kk < 16; ++kk) {
            half8 bf[2];
#pragma unroll
            for (int ct = 0; ct < 2; ++ct) {
                const int brow = ct * 16 + ll;
                const int ks = kk * 4 + lh;
                const int g2 = ks ^ (ks >> 1);
                const int byte = (brow * 1024 + g2 * 16) ^ ((brow & 7) << 4);
                bf[ct] = *reinterpret_cast<const half8*>(ldsh + byte);
            }
#pragma unroll
            for (int rt = 0; rt < 2; ++rt)
#pragma unroll
                for (int ct = 0; ct < 2; ++ct)
                    acc[rt][ct] = __builtin_amdgcn_mfma_f32_16x16x32_f16(
                        warr[rt][4 + kk], bf[ct], acc[rt][ct], 0, 0, 0);
        }

        // ---- lane-local cell (reg==gate), write h to swizzled bounce ----
#pragma unroll
        for (int rt = 0; rt < 2; ++rt)
#pragma unroll
            for (int ct = 0; ct < 2; ++ct) {
                f32x4 g4 = acc[rt][ct];
                const float gi = sigm_(g4[0]);
                const float gf = sigm_(g4[1]);
                const float gg = tanh_(g4[2]);
                const float go = sigm_(g4[3]);
                const float c  = gf * cst[rt][ct] + gi * gg;
                cst[rt][ct] = c;
                const float hn = go * tanh_(c);
                const int row = ct * 16 + ll;
                const int u   = wv * 8 + rt * 4 + lh;
                const int byte = (row * 128 + u * 2) ^ ((row & 7) << 4);
                *reinterpret_cast<h16*>(ldsb + byte) = (h16)hn;
            }
        __syncthreads();   // S2: bounce complete, all compute reads done

        // packed 8B agent-scope h store (write-through to L3)
        {
            const int byte = (srow * 128 + scol * 8) ^ ((srow & 7) << 4);
            ull pk = *reinterpret_cast<const ull*>(ldsb + byte);
            ull* dst = reinterpret_cast<ull*>(hcur + (size_t)sgb * H_ + ht * 64 + scol * 4);
            __hip_atomic_store(dst, pk, __ATOMIC_RELAXED, AGENT_);
        }
        // stage x(t+1) (x region free after S2)
        if (t + 1 < T_) {
            half8 r;
#pragma unroll
            for (int u = 0; u < 4; ++u) { r[u] = (h16)xr0[u]; r[4 + u] = (h16)xr1[u]; }
            *reinterpret_cast<half8*>(ldsx + xw_byte) = r;
        }
        __syncthreads();   // S3: drains h stores (vmcnt 0) for every wave

        if (t + 1 < T_) {
            if (tid == 0) {
                __hip_atomic_fetch_add(barp, 1u, __ATOMIC_RELEASE, AGENT_);
                const unsigned tgt = 8u * (unsigned)(t + 1);
                while (__hip_atomic_load(barp, __ATOMIC_ACQUIRE, AGENT_) < tgt)
                    __builtin_amdgcn_s_sleep(1);
            }
            __syncthreads();   // S4: group barrier passed
            // issue coalesced agent h loads for t+1 (lanes contiguous per instr)
            const ull* hp = reinterpret_cast<const ull*>(hcur + (size_t)sgb * H_);
#pragma unroll
            for (int i = 0; i < 8; ++i)
                hval[i] = __hip_atomic_load(hp + i * 16 + scol, __ATOMIC_RELAXED, AGENT_);
        }
    }
}

// features = hT @ Wfeat^T + bfeat ; out = features @ Wout^T + bout
__global__ void __launch_bounds__(256) final_kernel(
    const h16* __restrict__ hT, const float* __restrict__ Wfeat,
    const float* __restrict__ bfeat, const float* __restrict__ Wout,
    const float* __restrict__ bout, float* __restrict__ out)
{
    __shared__ __align__(16) h16 hsh[16][512];
    __shared__ float fsh[16][256];
    const int tid = threadIdx.x;
    const int b0  = blockIdx.x * 16;

    {
        const int row = tid >> 4, seg = tid & 15;
        const half8* s8 = reinterpret_cast<const half8*>(hT + (size_t)(b0 + row) * H_ + seg * 32);
        half8* d8 = reinterpret_cast<half8*>(&hsh[row][seg * 32]);
        d8[0] = s8[0]; d8[1] = s8[1]; d8[2] = s8[2]; d8[3] = s8[3];
    }
    __syncthreads();

    float acc[16];
#pragma unroll
    for (int b = 0; b < 16; ++b) acc[b] = 0.f;
    const float* wrow = Wfeat + (size_t)tid * H_;
    for (int k8 = 0; k8 < H_ / 8; ++k8) {
        f32x4 w0 = *reinterpret_cast<const f32x4*>(wrow + k8 * 8);
        f32x4 w1 = *reinterpret_cast<const f32x4*>(wrow + k8 * 8 + 4);
#pragma unroll
        for (int b = 0; b < 16; ++b) {
            half8 h8 = *reinterpret_cast<const half8*>(&hsh[b][k8 * 8]);
#pragma unroll
            for (int u = 0; u < 4; ++u) {
                acc[b] = fmaf(w0[u], (float)h8[u], acc[b]);
                acc[b] = fmaf(w1[u], (float)h8[4 + u], acc[b]);
            }
        }
    }
    const float bf = bfeat[tid];
#pragma unroll
    for (int b = 0; b < 16; ++b) fsh[b][tid] = acc[b] + bf;
    __syncthreads();

    if (tid < 32) {
        const int b = tid >> 1, oc = tid & 1;
        float a = bout[oc];
        const float* wo = Wout + oc * 256;
        for (int f = 0; f < 256; ++f) a = fmaf(wo[f], fsh[b][f], a);
        out[(size_t)(b0 + b) * 2 + oc] = a;
    }
}

extern "C" void kernel_launch(void* const* d_in, const int* in_sizes, int n_in,
                              void* d_out, int out_size, void* d_ws, size_t ws_size,
                              hipStream_t stream) {
    const float* x     = (const float*)d_in[0];
    const float* Wih   = (const float*)d_in[1];
    const float* Whh   = (const float*)d_in[2];
    const float* bih   = (const float*)d_in[3];
    const float* bhh   = (const float*)d_in[4];
    const float* Wfeat = (const float*)d_in[5];
    const float* bfeat = (const float*)d_in[6];
    const float* Wout  = (const float*)d_in[7];
    const float* bout  = (const float*)d_in[8];
    float* out = (float*)d_out;

    char* ws = (char*)d_ws;
    h16*      Wr    = (h16*)ws;                          // 2,621,440 B
    float*    biasr = (float*)(ws + 2621440);            // 8,192 B
    h16*      hbuf  = (h16*)(ws + 2621440 + 8192);       // 2,097,152 B
    unsigned* bar   = (unsigned*)(ws + 2621440 + 8192 + 2097152);  // 2,048 B

    prep_kernel<<<dim3((NR_ * Kc_ + 255) / 256), dim3(256), 0, stream>>>(
        Wih, Whh, bih, bhh, Wr, biasr, bar);

    void* args[] = {(void*)&x, (void*)&Wr, (void*)&biasr, (void*)&hbuf, (void*)&bar};
    hipLaunchCooperativeKernel((void*)lstm_kernel, dim3(256), dim3(512), args, 0, stream);

    const h16* hT = hbuf + (size_t)(B_ * H_);   // slot (T-1)&1 == 1
    final_kernel<<<dim3(B_ / 16), dim3(256), 0, stream>>>(hT, Wfeat, bfeat, Wout, bout, out);
}

// Round 5
// 1565.745 us; speedup vs baseline: 27.4609x; 2.6797x over previous
//
#include <hip/hip_runtime.h>

typedef _Float16 h16;
typedef __attribute__((ext_vector_type(8))) _Float16 half8;
typedef __attribute__((ext_vector_type(4))) float f32x4;
typedef unsigned long long ull;

#define B_   1024
#define T_   256
#define D_   128
#define H_   512
#define Kc_  640    // D + H
#define NR_  2048   // 4H rows, R-mapped
#define AGENT_ __HIP_MEMORY_SCOPE_AGENT

__device__ __forceinline__ float sigm_(float v) {
    return 1.0f / (1.0f + __expf(-v));
}
__device__ __forceinline__ float tanh_(float v) {
    v = fminf(15.0f, fmaxf(-15.0f, v));
    const float e = __expf(2.0f * v);
    return (e - 1.0f) / (e + 1.0f);
}

// Row shuffle: unit j, gate q (torch order i,f,g,o = src row q*512+j):
// R = (j>>2)*16 + (j&3)*4 + q. With C/D row=(lane>>4)*4+reg: reg==gate,
// unit lane-local -> pointwise cell needs no cross-lane.
__global__ void prep_kernel(const float* __restrict__ Wih, const float* __restrict__ Whh,
                            const float* __restrict__ bih, const float* __restrict__ bhh,
                            h16* __restrict__ Wr, float* __restrict__ biasr,
                            unsigned* __restrict__ bar) {
    int idx = blockIdx.x * 256 + threadIdx.x;
    if (idx < NR_ * Kc_) {
        int R = idx / Kc_, k = idx - R * Kc_;
        int Q = R >> 4, rw = R & 15;
        int j = Q * 4 + (rw >> 2), q = rw & 3;
        int src = q * H_ + j;
        float w = (k < D_) ? Wih[src * D_ + k] : Whh[src * H_ + (k - D_)];
        Wr[idx] = (h16)w;
    }
    if (idx < NR_) {
        int Q = idx >> 4, rw = idx & 15;
        int j = Q * 4 + (rw >> 2), q = rw & 3;
        int src = q * H_ + j;
        biasr[idx] = bih[src] + bhh[src];
    }
    if (idx < 1024)
        __hip_atomic_store(bar + idx, 0u, __ATOMIC_RELAXED, AGENT_);
}

// Persistent LSTM, cooperative launch, per-group (8-block) custom barriers.
// Block (bt = blk>>3, ht = blk&7): batch [bt*32,+32), units [ht*64,+64).
// The 32-row batch tile is split into halves A (rows 0-15) and B (16-31):
// two independent LSTM pipelines interleaved so each half's L3 h-exchange
// round-trip hides behind the other half's compute.
// All cross-block h traffic: agent-scope RELAXED atomics (L2-bypass, L3 is
// the single coherence point); ordering via __syncthreads vmcnt-drain before
// the counter RMW. No acquire/release -> no per-poll cache maintenance.
__global__ void __launch_bounds__(512, 2) lstm_kernel(
    const float* __restrict__ x,      // [B][T][D] fp32
    const h16*  __restrict__ Wr,      // [2048][640] fp16 (R-mapped)
    const float* __restrict__ biasr,  // [2048]
    h16* __restrict__ hbuf,           // [2][B][H] fp16 double buffer
    unsigned* __restrict__ bar)       // [32 groups][32] counters (A at +0, B at +16)
{
    __shared__ __align__(16) char ldsx[8192];     // [32 rows][16 gran16] x tile
    __shared__ __align__(16) char ldshA[16384];   // [16 rows][64 gran16] h half A
    __shared__ __align__(16) char ldshB[16384];
    __shared__ __align__(16) char ldsbA[2048];    // bounce [16 rows][64 u]*2B
    __shared__ __align__(16) char ldsbB[2048];

    const int blk = blockIdx.x;
    const int bt  = blk >> 3;          // 0..31 batch tile
    const int ht  = blk & 7;           // 0..7  unit tile
    const int tid = threadIdx.x;
    const int wv  = tid >> 6, l = tid & 63;
    const int ll  = l & 15, lh = l >> 4;
    const int Rb  = ht * 256 + wv * 32;   // wave's R-row base
    const int bbase = bt * 32;

    // ---- W slice -> registers (once, reused all 256 steps) ----
    half8 warr[2][20];
#pragma unroll
    for (int rt = 0; rt < 2; ++rt) {
        const h16* wbase = Wr + (size_t)(Rb + rt * 16 + ll) * Kc_ + lh * 8;
#pragma unroll
        for (int kc = 0; kc < 20; ++kc)
            warr[rt][kc] = *reinterpret_cast<const half8*>(wbase + kc * 32);
    }
    f32x4 bias4[2];
#pragma unroll
    for (int rt = 0; rt < 2; ++rt)
        bias4[rt] = *reinterpret_cast<const f32x4*>(biasr + Rb + rt * 16 + lh * 4);

    float cstA[2] = {0.f, 0.f}, cstB[2] = {0.f, 0.f};

    // x staging ids: thread (srow 0..31, scol 0..15), Gray+XOR swizzle
    const int srow = tid >> 4, scol = tid & 15;
    const int sgb  = bbase + srow;
    const int xw_byte = (srow * 256 + ((scol ^ (scol >> 1)) * 16)) ^ ((srow & 7) << 4);

    // h staging ids: thread (hrow 0..15, hcol 0..31); 4 ull pieces each
    const int hrow = tid >> 5, hcol = tid & 31;

    unsigned* barA = bar + bt * 32;
    unsigned* barB = bar + bt * 32 + 16;

    ull   hvA[4], hvB[4];
    f32x4 xr0, xr1;

    auto loadHalf = [&](const h16* hsrc, int rowoff, ull hv[4]) {
        const ull* hp = reinterpret_cast<const ull*>(hsrc + (size_t)(bbase + rowoff + hrow) * H_);
#pragma unroll
        for (int i = 0; i < 4; ++i)
            hv[i] = __hip_atomic_load(hp + i * 32 + hcol, __ATOMIC_RELAXED, AGENT_);
    };
    auto stageHalf = [&](char* ldsh, const ull hv[4]) {
#pragma unroll
        for (int i = 0; i < 4; ++i) {
            const int p  = i * 32 + hcol;          // 8B piece 0..127 in row
            const int g  = p >> 1, hf = p & 1;     // 16B granule + half
            const int g2 = g ^ (g >> 1);           // Gray
            const int byte = (hrow * 1024 + g2 * 16 + hf * 8) ^ ((hrow & 7) << 4);
            *reinterpret_cast<ull*>(ldsh + byte) = hv[i];
        }
    };
    auto computeHalf = [&](const char* ldsh, int ctbase, f32x4 acc[2]) {
#pragma unroll
        for (int kk = 0; kk < 4; ++kk) {           // x part: k = 0..128
            const int brow = ctbase + ll;
            const int ks = kk * 4 + lh;
            const int g2 = ks ^ (ks >> 1);
            const int byte = (brow * 256 + g2 * 16) ^ ((brow & 7) << 4);
            half8 bf = *reinterpret_cast<const half8*>(ldsx + byte);
#pragma unroll
            for (int rt = 0; rt < 2; ++rt)
                acc[rt] = __builtin_amdgcn_mfma_f32_16x16x32_f16(
                    warr[rt][kk], bf, acc[rt], 0, 0, 0);
        }
#pragma unroll
        for (int kk = 0; kk < 16; ++kk) {          // h part: k = 128..640
            const int ks = kk * 4 + lh;
            const int g2 = ks ^ (ks >> 1);
            const int byte = (ll * 1024 + g2 * 16) ^ ((ll & 7) << 4);
            half8 bf = *reinterpret_cast<const half8*>(ldsh + byte);
#pragma unroll
            for (int rt = 0; rt < 2; ++rt)
                acc[rt] = __builtin_amdgcn_mfma_f32_16x16x32_f16(
                    warr[rt][4 + kk], bf, acc[rt], 0, 0, 0);
        }
    };
    auto cellHalf = [&](f32x4 acc[2], float cst[2], char* ldsb) {
#pragma unroll
        for (int rt = 0; rt < 2; ++rt) {
            f32x4 g4 = acc[rt];
            const float gi = sigm_(g4[0]);
            const float gf = sigm_(g4[1]);
            const float gg = tanh_(g4[2]);
            const float go = sigm_(g4[3]);
            const float c  = gf * cst[rt] + gi * gg;
            cst[rt] = c;
            const float hn = go * tanh_(c);
            const int u = wv * 8 + rt * 4 + lh;
            const int byte = (ll * 128 + u * 2) ^ ((ll & 7) << 4);
            *reinterpret_cast<h16*>(ldsb + byte) = (h16)hn;
        }
    };
    auto storeHalf = [&](const char* ldsb, h16* hcur, int rowoff) {
        if (tid < 256) {
            const int r2 = tid >> 4, c2 = tid & 15;
            const int byte = (r2 * 128 + c2 * 8) ^ ((r2 & 7) << 4);
            ull pk = *reinterpret_cast<const ull*>(ldsb + byte);
            ull* dst = reinterpret_cast<ull*>(hcur + (size_t)(bbase + rowoff + r2) * H_ + ht * 64 + c2 * 4);
            __hip_atomic_store(dst, pk, __ATOMIC_RELAXED, AGENT_);
        }
    };

    // ---- prologue: zero h tiles, load+stage x(0) ----
    {
        half8 z;
#pragma unroll
        for (int u = 0; u < 8; ++u) z[u] = (h16)0.f;
        char* pA = ldshA + tid * 32;
        char* pB = ldshB + tid * 32;
        *reinterpret_cast<half8*>(pA) = z; *reinterpret_cast<half8*>(pA + 16) = z;
        *reinterpret_cast<half8*>(pB) = z; *reinterpret_cast<half8*>(pB + 16) = z;
        const float* xp = x + (size_t)sgb * T_ * D_ + scol * 8;
        xr0 = *reinterpret_cast<const f32x4*>(xp);
        xr1 = *reinterpret_cast<const f32x4*>(xp + 4);
        half8 r;
#pragma unroll
        for (int u = 0; u < 4; ++u) { r[u] = (h16)xr0[u]; r[4 + u] = (h16)xr1[u]; }
        *reinterpret_cast<half8*>(ldsx + xw_byte) = r;
    }
    __syncthreads();

    for (int t = 0; t < T_; ++t) {
        h16* hcur  = hbuf + (size_t)(t & 1) * (B_ * H_);
        const h16* hprev = hbuf + (size_t)((t & 1) ^ 1) * (B_ * H_);

        // ================= half A =================
        if (t > 0) stageHalf(ldshA, hvA);
        __syncthreads();                                   // S1A

        // issue x(t+1) prefetch (latency hidden under both halves' compute)
        if (t + 1 < T_) {
            const float* xp = x + ((size_t)sgb * T_ + (t + 1)) * D_ + scol * 8;
            xr0 = *reinterpret_cast<const f32x4*>(xp);
            xr1 = *reinterpret_cast<const f32x4*>(xp + 4);
        }

        f32x4 acc[2];
        acc[0] = bias4[0]; acc[1] = bias4[1];
        computeHalf(ldshA, 0, acc);
        cellHalf(acc, cstA, ldsbA);
        __syncthreads();                                   // S2A
        storeHalf(ldsbA, hcur, 0);
        __syncthreads();                                   // S3A: drains stores (vmcnt 0)
        if (t + 1 < T_ && tid == 0)
            __hip_atomic_fetch_add(barA, 1u, __ATOMIC_RELAXED, AGENT_);

        // wait for hB(t-1)  (round trip overlapped the whole A phase)
        if (t > 0) {
            if (tid == 0) {
                const unsigned tgt = 8u * (unsigned)t;
                while (__hip_atomic_load(barB, __ATOMIC_RELAXED, AGENT_) < tgt)
                    __builtin_amdgcn_s_sleep(1);
            }
            __syncthreads();                               // S4B
            loadHalf(hprev, 16, hvB);
            stageHalf(ldshB, hvB);
        }
        __syncthreads();                                   // S1B

        // ================= half B =================
        acc[0] = bias4[0]; acc[1] = bias4[1];
        computeHalf(ldshB, 16, acc);
        cellHalf(acc, cstB, ldsbB);
        __syncthreads();                                   // S2B
        storeHalf(ldsbB, hcur, 16);
        if (t + 1 < T_) {   // stage x(t+1): both halves' x(t) reads are done
            half8 r;
#pragma unroll
            for (int u = 0; u < 4; ++u) { r[u] = (h16)xr0[u]; r[4 + u] = (h16)xr1[u]; }
            *reinterpret_cast<half8*>(ldsx + xw_byte) = r;
        }
        __syncthreads();                                   // S3B: drains stores
        if (t + 1 < T_ && tid == 0)
            __hip_atomic_fetch_add(barB, 1u, __ATOMIC_RELAXED, AGENT_);

        // wait for hA(t)  (round trip overlapped the whole B phase)
        if (t + 1 < T_) {
            if (tid == 0) {
                const unsigned tgt = 8u * (unsigned)(t + 1);
                while (__hip_atomic_load(barA, __ATOMIC_RELAXED, AGENT_) < tgt)
                    __builtin_amdgcn_s_sleep(1);
            }
            __syncthreads();                               // S4A
            loadHalf(hcur, 0, hvA);
        }
    }
}

// features = hT @ Wfeat^T + bfeat ; out = features @ Wout^T + bout
__global__ void __launch_bounds__(256) final_kernel(
    const h16* __restrict__ hT, const float* __restrict__ Wfeat,
    const float* __restrict__ bfeat, const float* __restrict__ Wout,
    const float* __restrict__ bout, float* __restrict__ out)
{
    __shared__ __align__(16) h16 hsh[16][512];
    __shared__ float fsh[16][256];
    const int tid = threadIdx.x;
    const int b0  = blockIdx.x * 16;

    {
        const int row = tid >> 4, seg = tid & 15;
        const half8* s8 = reinterpret_cast<const half8*>(hT + (size_t)(b0 + row) * H_ + seg * 32);
        half8* d8 = reinterpret_cast<half8*>(&hsh[row][seg * 32]);
        d8[0] = s8[0]; d8[1] = s8[1]; d8[2] = s8[2]; d8[3] = s8[3];
    }
    __syncthreads();

    float acc[16];
#pragma unroll
    for (int b = 0; b < 16; ++b) acc[b] = 0.f;
    const float* wrow = Wfeat + (size_t)tid * H_;
    for (int k8 = 0; k8 < H_ / 8; ++k8) {
        f32x4 w0 = *reinterpret_cast<const f32x4*>(wrow + k8 * 8);
        f32x4 w1 = *reinterpret_cast<const f32x4*>(wrow + k8 * 8 + 4);
#pragma unroll
        for (int b = 0; b < 16; ++b) {
            half8 h8 = *reinterpret_cast<const half8*>(&hsh[b][k8 * 8]);
#pragma unroll
            for (int u = 0; u < 4; ++u) {
                acc[b] = fmaf(w0[u], (float)h8[u], acc[b]);
                acc[b] = fmaf(w1[u], (float)h8[4 + u], acc[b]);
            }
        }
    }
    const float bf = bfeat[tid];
#pragma unroll
    for (int b = 0; b < 16; ++b) fsh[b][tid] = acc[b] + bf;
    __syncthreads();

    if (tid < 32) {
        const int b = tid >> 1, oc = tid & 1;
        float a = bout[oc];
        const float* wo = Wout + oc * 256;
        for (int f = 0; f < 256; ++f) a = fmaf(wo[f], fsh[b][f], a);
        out[(size_t)(b0 + b) * 2 + oc] = a;
    }
}

extern "C" void kernel_launch(void* const* d_in, const int* in_sizes, int n_in,
                              void* d_out, int out_size, void* d_ws, size_t ws_size,
                              hipStream_t stream) {
    const float* x     = (const float*)d_in[0];
    const float* Wih   = (const float*)d_in[1];
    const float* Whh   = (const float*)d_in[2];
    const float* bih   = (const float*)d_in[3];
    const float* bhh   = (const float*)d_in[4];
    const float* Wfeat = (const float*)d_in[5];
    const float* bfeat = (const float*)d_in[6];
    const float* Wout  = (const float*)d_in[7];
    const float* bout  = (const float*)d_in[8];
    float* out = (float*)d_out;

    char* ws = (char*)d_ws;
    h16*      Wr    = (h16*)ws;                          // 2,621,440 B
    float*    biasr = (float*)(ws + 2621440);            // 8,192 B
    h16*      hbuf  = (h16*)(ws + 2621440 + 8192);       // 2,097,152 B
    unsigned* bar   = (unsigned*)(ws + 2621440 + 8192 + 2097152);  // 4,096 B

    prep_kernel<<<dim3((NR_ * Kc_ + 255) / 256), dim3(256), 0, stream>>>(
        Wih, Whh, bih, bhh, Wr, biasr, bar);

    void* args[] = {(void*)&x, (void*)&Wr, (void*)&biasr, (void*)&hbuf, (void*)&bar};
    hipLaunchCooperativeKernel((void*)lstm_kernel, dim3(256), dim3(512), args, 0, stream);

    const h16* hT = hbuf + (size_t)(B_ * H_);   // slot (T-1)&1 == 1
    final_kernel<<<dim3(B_ / 16), dim3(256), 0, stream>>>(hT, Wfeat, bfeat, Wout, bout, out);
}